// Round 7
// baseline (141.563 us; speedup 1.0000x reference)
//
#include <hip/hip_runtime.h>
#include <hip/hip_bf16.h>
#include <float.h>

#define Bc 32
#define Nc 512
#define Dc 128
#define Hc 8
#define DKc 16
#define Ec 128
#define LOG2E 1.44269504088896340736f
#define SCLAMP 80.0f
#define KPAD 3.0e38f

typedef __attribute__((ext_vector_type(4))) short s16x4;
typedef __attribute__((ext_vector_type(8))) short s16x8;
typedef __attribute__((ext_vector_type(4))) float f32x4;

union BFU { __hip_bfloat16 b; short s; };
static __device__ inline short f2bf(float f) { BFU u; u.b = __float2bfloat16(f); return u.s; }
static __device__ inline s16x4 pack4(float a, float b, float c, float d) {
  s16x4 r; r[0] = f2bf(a); r[1] = f2bf(b); r[2] = f2bf(c); r[3] = f2bf(d); return r;
}

#if __has_builtin(__builtin_amdgcn_exp2f)
#define EXP2F(x) __builtin_amdgcn_exp2f(x)
#else
#define EXP2F(x) exp2f(x)
#endif

// D = A*B + C for 16x16x16 bf16. A[m=l&15][k=(l>>4)*4+i]; B[k=(l>>4)*4+i][n=l&15];
// C/D: col(n)=l&15, row(m)=(l>>4)*4+reg.
static __device__ inline f32x4 mfma16(s16x4 a, s16x4 b, f32x4 c) {
#if __has_builtin(__builtin_amdgcn_mfma_f32_16x16x16bf16_1k)
  return __builtin_amdgcn_mfma_f32_16x16x16bf16_1k(a, b, c, 0, 0, 0);
#else
  int lane = threadIdx.x & 63;
  int g = lane >> 4, base = lane & 15;
  int src0 = (base + 32 * g) & 63;
  int src1 = (base + 32 * g + 16) & 63;
  int ax = ((int*)&a)[0], ay = ((int*)&a)[1];
  int bx = ((int*)&b)[0], by = ((int*)&b)[1];
  int A0 = __shfl(ax, src0), A1 = __shfl(ay, src0);
  int A2 = __shfl(ax, src1), A3 = __shfl(ay, src1);
  int B0 = __shfl(bx, src0), B1 = __shfl(by, src0);
  int B2 = __shfl(bx, src1), B3 = __shfl(by, src1);
  if (g >= 2) { A0 = A1 = A2 = A3 = 0; B0 = B1 = B2 = B3 = 0; }
  s16x8 A8, B8;
  ((int*)&A8)[0] = A0; ((int*)&A8)[1] = A1; ((int*)&A8)[2] = A2; ((int*)&A8)[3] = A3;
  ((int*)&B8)[0] = B0; ((int*)&B8)[1] = B1; ((int*)&B8)[2] = B2; ((int*)&B8)[3] = B3;
  return __builtin_amdgcn_mfma_f32_16x16x32_bf16(A8, B8, c, 0, 0, 0);
#endif
}

// ---- MLP eval helpers (f32, fully unrolled, static indexing) ----
static __device__ __forceinline__ void h2pre_eval(
    float e, const float* W1, const float* B1, const float* W2, const float* B2,
    float* h2)
{
  float h1[16];
  #pragma unroll
  for (int u = 0; u < 16; ++u) h1[u] = fmaxf(0.f, fmaf(e, W1[u], B1[u]));
  #pragma unroll
  for (int v = 0; v < 16; ++v) {
    float a = B2[v];
    #pragma unroll
    for (int u = 0; u < 16; ++u) a = fmaf(h1[u], W2[u * 16 + v], a);
    h2[v] = a;
  }
}
static __device__ __forceinline__ void bias_eval(
    float e, const float* W1, const float* B1, const float* W2, const float* B2,
    const float* W3, const float* B3, float* bias8)
{
  float h2[16];
  h2pre_eval(e, W1, B1, W2, B2, h2);
  #pragma unroll
  for (int h = 0; h < 8; ++h) {
    float a = B3[h];
    #pragma unroll
    for (int v = 0; v < 16; ++v) a = fmaf(fmaxf(h2[v], 0.f), W3[v * 8 + h], a);
    bias8[h] = a;
  }
}

// ---- prep: weight converter (0..255) + mask detector (256) + PWL tablegen (257) ----
// knotsG: f32[512] sorted, padded KPAD.  coeffG: f32 [8h][320seg][2] (a,c)*LOG2E.
__global__ __launch_bounds__(256) void prep_kernel(
    const float* __restrict__ Wq, const float* __restrict__ Wk, const float* __restrict__ Wv,
    const float* __restrict__ Wo,
    const unsigned char* __restrict__ m, int* __restrict__ flag,
    short* __restrict__ Wt, short* __restrict__ Wob,
    const float* __restrict__ mW1, const float* __restrict__ mb1,
    const float* __restrict__ mW2, const float* __restrict__ mb2,
    const float* __restrict__ mW3, const float* __restrict__ mb3,
    float* __restrict__ knotsG, float* __restrict__ coeffG)
{
  int blk = blockIdx.x;
  int t = threadIdx.x;

  if (blk == 256) {   // mask-format detector (single-writer)
    __shared__ int red[4];
    int any = 0;
    for (int u = t; u < 16384; u += 256)
      if ((u & 3) != 0 && m[u] != 0) any = 1;
    unsigned long long bal = __ballot(any != 0);
    if ((t & 63) == 0) red[t >> 6] = (bal != 0ULL) ? 1 : 0;
    __syncthreads();
    if (t == 0) *flag = red[0] | red[1] | red[2] | red[3];
    return;
  }

  if (blk == 257) {   // PWL table generation
    __shared__ float t1raw[16], t1s[16];
    __shared__ float ks[512], ks2[512];
    __shared__ int cnt, n1s;

    if (t < 16) {
      float w = mW1[t];
      t1raw[t] = (w != 0.f) ? (-mb1[t] / w) : KPAD;
    }
    for (int u = t; u < 512; u += 256) { ks[u] = KPAD; ks2[u] = KPAD; }
    __syncthreads();
    if (t < 16) {   // rank-sort 16 (stable)
      float v = t1raw[t];
      int r = 0;
      #pragma unroll
      for (int j = 0; j < 16; ++j) {
        float vj = t1raw[j];
        r += (vj < v) || (vj == v && j < t);
      }
      t1s[r] = v;
    }
    __syncthreads();
    if (t == 0) {   // copy finite knots to ks, count
      int n1 = 0;
      while (n1 < 16 && t1s[n1] < 1.0e37f) { ks[n1] = t1s[n1]; n1++; }
      n1s = n1;
      cnt = n1;
    }
    __syncthreads();
    int n1 = n1s;
    // layer-2 relu-crossing candidates: one thread per interval (n1+1 intervals)
    if (t <= n1) {
      bool first = (t == 0), last = (t == n1);
      float L = first ? 0.f : t1s[t - 1];
      float R = last ? 0.f : t1s[t];
      float p1, p2;
      bool ok = true;
      if (first && last) { p1 = 0.f; p2 = 1.f; }
      else if (first)    { p1 = R - 1.f; p2 = R - 0.5f; }
      else if (last)     { p1 = L + 0.5f; p2 = L + 1.f; }
      else {
        float w = R - L;
        if (w > 0.f) { p1 = L + 0.25f * w; p2 = L + 0.75f * w; }
        else ok = false;
      }
      if (ok && p2 > p1) {
        float h2a[16], h2b[16];
        h2pre_eval(p1, mW1, mb1, mW2, mb2, h2a);
        h2pre_eval(p2, mW1, mb1, mW2, mb2, h2b);
        #pragma unroll
        for (int v = 0; v < 16; ++v) {
          float bet = (h2b[v] - h2a[v]) / (p2 - p1);
          float alp = fmaf(-bet, p1, h2a[v]);
          float x = -alp / bet;
          bool fin = (x == x) && (fabsf(x) < 1.0e37f) && (bet != 0.f);
          bool inr = (first || x > L) && (last || x < R);
          if (fin && inr) { int id = atomicAdd(&cnt, 1); ks[id] = x; }
        }
      }
    }
    __syncthreads();
    int mknots = cnt;   // <= 288
    // rank-sort first mknots entries into ks2
    for (int i = t; i < mknots; i += 256) {
      float v = ks[i];
      int r = 0;
      for (int j = 0; j < mknots; ++j) {
        float vj = ks[j];
        r += (vj < v) || (vj == v && j < i);
      }
      ks2[r] = v;
    }
    __syncthreads();
    for (int u = t; u < 512; u += 256) knotsG[u] = ks2[u];
    // per-segment coefficients
    for (int s = t; s < mknots + 1; s += 256) {
      bool first = (s == 0), last = (s == mknots);
      float L = first ? 0.f : ks2[s - 1];
      float R = last ? 0.f : ks2[s];
      float p1, p2;
      if (first && last) { p1 = 0.f; p2 = 1.f; }
      else if (first)    { p1 = R - 1.f; p2 = R - 0.5f; }
      else if (last)     { p1 = L + 0.5f; p2 = L + 1.f; }
      else { float w = R - L; p1 = L + 0.25f * w; p2 = L + 0.75f * w; }
      float ba[8];
      bias_eval(p1, mW1, mb1, mW2, mb2, mW3, mb3, ba);
      if (p2 > p1) {
        float bb[8];
        bias_eval(p2, mW1, mb1, mW2, mb2, mW3, mb3, bb);
        #pragma unroll
        for (int h = 0; h < 8; ++h) {
          float sl = (bb[h] - ba[h]) / (p2 - p1);
          float c0 = fmaf(-sl, p1, ba[h]);
          coeffG[h * 640 + s * 2]     = sl * LOG2E;
          coeffG[h * 640 + s * 2 + 1] = c0 * LOG2E;
        }
      } else {
        #pragma unroll
        for (int h = 0; h < 8; ++h) {
          coeffG[h * 640 + s * 2]     = 0.f;
          coeffG[h * 640 + s * 2 + 1] = ba[h] * LOG2E;
        }
      }
    }
    return;
  }

  int o = blk * 256 + t;
  if (o < 49152) {
    int mat = o >> 14, r = o & 16383;
    int hk = r >> 7, d = r & 127;
    const float* src = (mat == 0) ? Wq : ((mat == 1) ? Wk : Wv);
    Wt[o] = f2bf(src[(hk >> 4) * 2048 + d * 16 + (hk & 15)]);
  } else {
    int o2 = o - 49152;
    int et = o2 >> 11, s = (o2 >> 8) & 7, lane = (o2 >> 2) & 63, i = o2 & 3;
    Wob[o2] = f2bf(Wo[(s * 16 + (lane >> 4) * 4 + i) * 128 + et * 16 + (lane & 15)]);
  }
}

// ---- kernel A: QKV projection via MFMA (unchanged from round 5/6) ----
__global__ __launch_bounds__(256, 4) void qkv4(
    const float* __restrict__ q, const short* __restrict__ Wt,
    short* __restrict__ Qb, short* __restrict__ Kb, short* __restrict__ Vt)
{
  __shared__ short qs[16][136];
  int blk = blockIdx.x;
  int b = blk >> 5;
  int rt = (blk & 31) << 4;
  int t = threadIdx.x;
  int wid = t >> 6, lane = t & 63;
  int lq = lane & 15, lg = lane >> 4;

  #pragma unroll
  for (int it = 0; it < 2; ++it) {
    int u = t + it * 256;
    int row = u >> 5, c4 = (u & 31) << 2;
    float4 v = *(const float4*)&q[((((b << 9) + rt + row) << 7)) + c4];
    *(s16x4*)&qs[row][c4] = pack4(v.x, v.y, v.z, v.w);
  }
  __syncthreads();

  s16x4 af[8];
  #pragma unroll
  for (int ks = 0; ks < 8; ++ks)
    af[ks] = *(const s16x4*)&qs[lq][ks * 16 + lg * 4];

  #pragma unroll 1
  for (int pj = 0; pj < 3; ++pj) {
    const short* Wm = Wt + pj * 16384;
    #pragma unroll
    for (int c2 = 0; c2 < 2; ++c2) {
      int ct = wid * 2 + c2;
      f32x4 acc = (f32x4)0.f;
      #pragma unroll
      for (int ks = 0; ks < 8; ++ks) {
        s16x4 bf = *(const s16x4*)&Wm[(ct * 16 + lq) * 128 + ks * 16 + lg * 4];
        acc = mfma16(af[ks], bf, acc);
      }
      if (pj == 0) {
        s16x4 pk = pack4(acc[0] * (0.25f * LOG2E), acc[1] * (0.25f * LOG2E),
                         acc[2] * (0.25f * LOG2E), acc[3] * (0.25f * LOG2E));
        #pragma unroll
        for (int r = 0; r < 4; ++r)
          Qb[(ct << 18) + (b << 13) + ((rt + lg * 4 + r) << 4) + lq] = pk[r];
      } else if (pj == 1) {
        s16x4 pk = pack4(acc[0], acc[1], acc[2], acc[3]);
        #pragma unroll
        for (int r = 0; r < 4; ++r)
          Kb[(ct << 18) + (b << 13) + ((rt + lg * 4 + r) << 4) + lq] = pk[r];
      } else {
        s16x4 pk = pack4(acc[0], acc[1], acc[2], acc[3]);
        *(s16x4*)&Vt[(ct << 18) + (((b << 4) + lq) << 9) + rt + lg * 4] = pk;
      }
    }
  }
}

// branchless lower-bound over 512-padded sorted knots: returns count of knots <= e
static __device__ __forceinline__ int segof(const float* knotsL, float e) {
  int p = 0;
  #pragma unroll
  for (int s = 256; s > 0; s >>= 1)
    p += (knotsL[p + s - 1] <= e) ? s : 0;
  return p;
}

// ---- kernel B: PWL edge-bias + masked softmax attention + MFMA out-projection ----
// Block = (b, 16 q-rows); 4 waves each own 8 of the 32 key-chunks (no main-loop barriers).
// LDS main loop: knots f32[512] @0 (2KB) + coeff [8][320][2] f32 @2048 (20KB).
// Epilogue overlay: d2 partials [4][128][17] f32 @0 (34816B) + psum [4][8][16] @34816 (2048B).
__global__ __launch_bounds__(256, 4) void attn7(
    const float* __restrict__ edge, const unsigned char* __restrict__ maskB,
    const int* __restrict__ flag,
    const short* __restrict__ Qb, const short* __restrict__ Kb, const short* __restrict__ Vt,
    const short* __restrict__ Wob,
    const float* __restrict__ knotsG, const float* __restrict__ coeffG,
    float* __restrict__ out)
{
  __shared__ __align__(16) char smem[36864];

  int t = threadIdx.x;
  int wid = t >> 6, lane = t & 63;
  int lq = lane & 15, lg = lane >> 4;
  int b = blockIdx.x >> 5;
  int qt = (blockIdx.x & 31) << 4;
  int mflag = *flag;

  float* knotsL = (float*)smem;            // [512]
  float* coeffL = (float*)(smem + 2048);   // [8][320][2]
  float* d2L = (float*)smem;               // epilogue overlay [4][128][17]
  float* psL = (float*)(smem + 34816);     // [4][8][16]

  // stage PWL table (knotsG and coeffG are contiguous: 512 + 5120 = 5632 f32)
  for (int u = t; u < 1408; u += 256)
    ((float4*)smem)[u] = ((const float4*)knotsG)[u];

  const short* Kl = Kb + (b << 13) + (lq << 4) + (lg << 2);
  const short* Vl = Vt + (((b << 4) + lq) << 9) + (lg << 2);
  const short* Ql = Qb + (b << 13) + ((qt + lq) << 4) + (lg << 2);
  unsigned mbase = (((b << 9) + qt + lq) << 9) + (lg << 2);   // [b][q=qt+lq][j] layout

  s16x4 qf[8];
  #pragma unroll
  for (int h = 0; h < 8; ++h) qf[h] = *(const s16x4*)(Ql + (h << 18));

  f32x4 oacc[8];
  float psum[8];
  #pragma unroll
  for (int h = 0; h < 8; ++h) { oacc[h] = (f32x4)0.f; psum[h] = 0.f; }

  // prologue: this wave's chunk 0 (edge + mask, same addressing)
  int jb = wid << 4;
  float4 ev = *(const float4*)&edge[mbase + jb];
  int4 mkv;
  if (mflag) {
    uchar4 u = *(const uchar4*)&maskB[mbase + jb];
    mkv.x = u.x; mkv.y = u.y; mkv.z = u.z; mkv.w = u.w;
  } else {
    mkv = *(const int4*)&((const int*)maskB)[mbase + jb];
  }

  __syncthreads();   // table staged

  #pragma unroll 1
  for (int cc = 0; cc < 8; ++cc) {
    jb = ((cc << 2) | wid) << 4;

    float4 evn; int4 mkn;
    if (cc < 7) {
      int jbn = (((cc + 1) << 2) | wid) << 4;
      evn = *(const float4*)&edge[mbase + jbn];
      if (mflag) {
        uchar4 u = *(const uchar4*)&maskB[mbase + jbn];
        mkn.x = u.x; mkn.y = u.y; mkn.z = u.z; mkn.w = u.w;
      } else {
        mkn = *(const int4*)&((const int*)maskB)[mbase + jbn];
      }
    } else { evn = ev; mkn = mkv; }

    s16x4 kf[8];
    #pragma unroll
    for (int h = 0; h < 8; ++h) kf[h] = *(const s16x4*)(Kl + (h << 18) + (jb << 4));

    // PWL segment lookup for this lane's 4 edges (j = jb+lg*4+r, q = qt+lq)
    int sg0 = segof(knotsL, ev.x);
    int sg1 = segof(knotsL, ev.y);
    int sg2 = segof(knotsL, ev.z);
    int sg3 = segof(knotsL, ev.w);
    const float* c0 = coeffL + (sg0 << 1);
    const float* c1 = coeffL + (sg1 << 1);
    const float* c2 = coeffL + (sg2 << 1);
    const float* c3 = coeffL + (sg3 << 1);

    // per-head: S^T = K.Q^T + bias(e) ; p = exp2(min(sc,80)) ; O^T += V^T.P^T
    #pragma unroll
    for (int h = 0; h < 8; ++h) {
      int hb = h * 640;
      float2 a0 = *(const float2*)(c0 + hb);
      float2 a1 = *(const float2*)(c1 + hb);
      float2 a2 = *(const float2*)(c2 + hb);
      float2 a3 = *(const float2*)(c3 + hb);
      f32x4 sc;
      sc[0] = fmaf(a0.x, ev.x, a0.y);
      sc[1] = fmaf(a1.x, ev.y, a1.y);
      sc[2] = fmaf(a2.x, ev.z, a2.y);
      sc[3] = fmaf(a3.x, ev.w, a3.y);
      sc = mfma16(kf[h], qf[h], sc);
      s16x4 vf = *(const s16x4*)(Vl + (h << 18) + jb);
      float p0 = mkv.x ? 0.f : EXP2F(fminf(sc[0], SCLAMP));
      float p1 = mkv.y ? 0.f : EXP2F(fminf(sc[1], SCLAMP));
      float p2 = mkv.z ? 0.f : EXP2F(fminf(sc[2], SCLAMP));
      float p3 = mkv.w ? 0.f : EXP2F(fminf(sc[3], SCLAMP));
      psum[h] += (p0 + p1) + (p2 + p3);
      s16x4 pf = pack4(p0, p1, p2, p3);
      oacc[h] = mfma16(vf, pf, oacc[h]);
    }
    ev = evn; mkv = mkn;
  }

  // ---- epilogue: cross-wave psum, normalize, MFMA out-projection, merge ----
  #pragma unroll
  for (int h = 0; h < 8; ++h) {
    float s = psum[h];
    s += __shfl_xor(s, 16);
    s += __shfl_xor(s, 32);
    psum[h] = s;
  }
  if (lg == 0) {
    #pragma unroll
    for (int h = 0; h < 8; ++h) psL[wid * 128 + h * 16 + lq] = psum[h];
  }
  __syncthreads();

  s16x4 obf[8];
  #pragma unroll
  for (int h = 0; h < 8; ++h) {
    float tot = psL[h * 16 + lq] + psL[128 + h * 16 + lq]
              + psL[256 + h * 16 + lq] + psL[384 + h * 16 + lq];
    float inv = (tot > 0.f) ? 1.f / tot : 0.f;
    obf[h] = pack4(oacc[h][0] * inv, oacc[h][1] * inv, oacc[h][2] * inv, oacc[h][3] * inv);
  }

  f32x4 d2a[8];
  #pragma unroll
  for (int et = 0; et < 8; ++et) d2a[et] = (f32x4)0.f;
  #pragma unroll
  for (int s = 0; s < 8; ++s) {
    #pragma unroll
    for (int et = 0; et < 8; ++et) {
      s16x4 wo = *(const s16x4*)&Wob[((et * 8 + s) << 8) + (lane << 2)];
      d2a[et] = mfma16(wo, obf[s], d2a[et]);
    }
  }

  #pragma unroll
  for (int et = 0; et < 8; ++et)
    #pragma unroll
    for (int r = 0; r < 4; ++r)
      d2L[(wid * 128 + et * 16 + lg * 4 + r) * 17 + lq] = d2a[et][r];
  __syncthreads();

  #pragma unroll
  for (int k = 0; k < 2; ++k) {
    int et = wid * 2 + k;
    #pragma unroll
    for (int r = 0; r < 4; ++r) {
      int el = (et * 16 + lg * 4 + r) * 17 + lq;
      float v = d2L[el] + d2L[2176 + el] + d2L[4352 + el] + d2L[6528 + el];
      out[(((b << 9) + qt + lq) << 7) + et * 16 + lg * 4 + r] = v;
    }
  }
}

extern "C" void kernel_launch(void* const* d_in, const int* in_sizes, int n_in,
                              void* d_out, int out_size, void* d_ws, size_t ws_size,
                              hipStream_t stream)
{
  const float* q    = (const float*)d_in[0];
  const unsigned char* mask = (const unsigned char*)d_in[1];
  const float* edge = (const float*)d_in[2];
  const float* Wq   = (const float*)d_in[3];
  const float* Wk   = (const float*)d_in[4];
  const float* Wv   = (const float*)d_in[5];
  const float* Wo   = (const float*)d_in[6];
  const float* mW1  = (const float*)d_in[7];
  const float* mb1  = (const float*)d_in[8];
  const float* mW2  = (const float*)d_in[9];
  const float* mb2  = (const float*)d_in[10];
  const float* mW3  = (const float*)d_in[11];
  const float* mb3  = (const float*)d_in[12];
  float* out = (float*)d_out;

  size_t per = (size_t)Hc * Bc * Nc * DKc;     // 2,097,152 bf16 elems per matrix
  short* Wt  = (short*)d_ws;                   // 49152
  short* Wob = Wt + 49152;                     // 16384
  short* Qb  = Wob + 16384;
  short* Kb  = Qb + per;
  short* Vt  = Kb + per;
  float* knotsG = (float*)(Vt + per);          // 512 f32 (16B-aligned)
  float* coeffG = knotsG + 512;                // 5120 f32
  int* flag  = (int*)(coeffG + 5120);          // ~12.74 MB used

  prep_kernel<<<dim3(258), dim3(256), 0, stream>>>(Wq, Wk, Wv, Wo, mask, flag, Wt, Wob,
      mW1, mb1, mW2, mb2, mW3, mb3, knotsG, coeffG);
  qkv4<<<dim3(Bc * 32), dim3(256), 0, stream>>>(q, Wt, Qb, Kb, Vt);
  attn7<<<dim3(Bc * 32), dim3(256), 0, stream>>>(edge, mask, flag, Qb, Kb, Vt, Wob,
      knotsG, coeffG, out);
}